// Round 15
// baseline (1984.655 us; speedup 1.0000x reference)
//
#include <hip/hip_runtime.h>

// CharNNClassifier: out = (LSTM(emb[x]) last h) @ W_out^T + b_out
// B=256 S=512 V=256 E=128 H=256 4H=1024 O=128, fp32 in/out.
//
// R17 = R16 + split-k phase overlap (break MFMA/VALU additivity).
//  R16 post-mortem: VALU-count diet flat -> count lever exhausted. Step
//  3600 cyc = MFMA-issue 2064 + VALU-issue 1368, additive ONLY because
//  barrier lockstep phases all waves together (m114: the pipes co-run
//  across waves when de-phased).
//  R17 mechanism: k-split the serial chain. MFMA k<128 needs only h-low
//  (p=0 epilogue outputs); k>=128 needs only h-high (p=1). Per step:
//    epi-low -> bar -> {kt0..3 MFMA || epi-high VALU interleaved} -> bar
//    -> kt4..7 MFMA.
//  The epi-high VALU + tcv/wstr/x prefetches issue under the MFMA pipe;
//  barriers de-phase waves for cross-wave packing. Cost: 2 barriers/step
//  (drain-free), +~9 regs (g1 saves, tcv pipeline).
//  Base (R16): kt0,1 wlds | kt2,4,5,6 wreg[8][4] | kt3,7 streamed from
//  Wpk[tid][frag]; A-frags read once; row-trick epilogue; HSTRIDE 272.
//  LDS = 128K + 4.25K + 0.5K = 132.75 KB. Regs ~224/256.
//  CANARY: WRITE_SIZE > 10 MB = spill -> revert to R15, declare ceiling.

typedef _Float16 f16x8 __attribute__((ext_vector_type(8)));
typedef _Float16 f16x4 __attribute__((ext_vector_type(4)));
typedef float    f32x4 __attribute__((ext_vector_type(4)));

#define B_  256
#define S_  512
#define V_  256
#define E_  128
#define H_  256
#define O_  128

// ws layout (bytes)
#define T_OFF     0u              // T2h: 256*256*4 fp16 = 512 KiB
#define HLAST_OFF (512u << 10)    // hlast: 256*256*4B   = 256 KiB
#define WPK_OFF   (768u << 10)    // Wpk: 512thr*16frag*16B = 128 KiB

// ---------------------------------------------------------------- K1: table
// T2h[v][unit] = fp16x4 {i,f,g,o} pre-activations from the embedding path.
__global__ void build_table(const float* __restrict__ emb,
                            const float* __restrict__ W_ih,
                            const float* __restrict__ b_ih,
                            const float* __restrict__ b_hh,
                            _Float16* __restrict__ T2h) {
    const int v   = blockIdx.x;   // vocab id
    const int tid = threadIdx.x;  // 256 threads = hidden unit

    __shared__ float e[E_];
    if (tid < E_) e[tid] = emb[v * E_ + tid];
    __syncthreads();

    f16x4 tv;
#pragma unroll
    for (int t = 0; t < 4; ++t) {
        const int g = t * 256 + tid;
        const float4* wp = (const float4*)(W_ih + g * E_);
        float acc = 0.f;
#pragma unroll
        for (int i = 0; i < E_ / 4; ++i) {
            float4 w = wp[i];
            acc += w.x * e[4*i] + w.y * e[4*i+1] + w.z * e[4*i+2] + w.w * e[4*i+3];
        }
        tv[t] = (_Float16)(acc + b_ih[g] + b_hh[g]);
    }
    *(f16x4*)(T2h + ((size_t)v * 256 + tid) * 4) = tv;
}

// ------------------------------------------------------- K1b: W-frag prepack
// Wpk[tid][blk] (blk = ktS*8 + j, kt = 3 + ktS*4): each thread's 16 frags
// CONTIGUOUS (256 B) so the main kernel's loads fold into offset imms.
__global__ void prepack(const float* __restrict__ W_hh,
                        _Float16* __restrict__ Wpk) {
    const int blk = blockIdx.x;      // 0..15 = ktS*8 + j
    const int ktS = blk >> 3;        // 0 -> kt3, 1 -> kt7
    const int j   = blk & 7;
    const int kt  = 3 + ktS * 4;
    const int tid = threadIdx.x;     // 512
    const int wv = tid >> 6, l = tid & 63, l15 = l & 15, quad = l >> 4;
    const int n  = j * 128 + wv * 16 + l15;   // gate column
    const int k0 = kt * 32 + quad * 8;
    const float4* wp = (const float4*)(W_hh + (size_t)n * H_ + k0);
    float4 w0 = wp[0];
    float4 w1 = wp[1];
    f16x8 f = (f16x8){
        (_Float16)w0.x, (_Float16)w0.y, (_Float16)w0.z, (_Float16)w0.w,
        (_Float16)w1.x, (_Float16)w1.y, (_Float16)w1.z, (_Float16)w1.w};
    *(f16x8*)(Wpk + ((size_t)tid * 16 + blk) * 8) = f;
}

// ------------------------------------------------------------ K2: recurrence
// Pre-act bounds: |W_hh row . h| <= 256*(1/16) = 16 hard; |table| < ~5.
// Sigmoid needs no clamp; tanh keeps a +-30 clamp as overflow insurance.
__device__ __forceinline__ float sig_fast(float x) {
    float t = __builtin_amdgcn_exp2f(-1.4426950408889634f * x);
    return __builtin_amdgcn_rcpf(1.f + t);
}
__device__ __forceinline__ float tanh_fast(float x) {
    x = fminf(fmaxf(x, -30.f), 30.f);
    float t = __builtin_amdgcn_exp2f(-2.8853900817779268f * x);  // e^{-2x}
    return (1.f - t) * __builtin_amdgcn_rcpf(1.f + t);
}

#define HSTRIDE 272   // fp16/row: 544 B => row bank-phase 0/8/16/24

__launch_bounds__(512, 2)
__global__ void lstm_persistent(const int* __restrict__ x,
                                const float* __restrict__ W_hh,
                                const _Float16* __restrict__ T2h,
                                const _Float16* __restrict__ Wpk,
                                float* __restrict__ hlast) {
    const int tid    = threadIdx.x;
    const int wv     = tid >> 6;     // wave 0..7
    const int l      = tid & 63;
    const int l15    = l & 15;
    const int quad   = l >> 4;       // 0..3  == this lane's batch row (local)
    const int stripe = blockIdx.x;   // batch rows [stripe*4, +4)
    const int uu     = wv * 16 + l15;    // unit (p=0 half)

    // LDS: 128 KB weights (kt 0..1) + 4-row h dbuf + zero block.
    __shared__ __align__(16) _Float16 wlds[8][8][2][512];   // 128 KiB
    __shared__ __align__(16) _Float16 hbuf[2][4][HSTRIDE];  // 4.25 KiB
    __shared__ __align__(16) _Float16 zbuf[256];            // 512 B zeros

    if (tid < 128) ((int*)zbuf)[tid] = 0;

    // ---- prologue: kt {0,1}->wlds, {2,4,5,6}->wreg, {3,7} streamed later.
    // col n = j*128 + uu; k = kt*32 + quad*8 + i; B[k][n] = W_hh[n][k]
    f16x8 wreg[8][4];   // [j][m]: m=0->kt2, 1->kt4, 2->kt5, 3->kt6
#pragma unroll
    for (int j = 0; j < 8; ++j) {
        const float* wr = W_hh + (size_t)(j * 128 + uu) * H_ + quad * 8;
#pragma unroll
        for (int kt = 0; kt < 7; ++kt) {
            if (kt == 3) continue;   // streamed
            const float4* wp = (const float4*)(wr + kt * 32);
            float4 w0 = wp[0];
            float4 w1 = wp[1];
            f16x8 f = (f16x8){
                (_Float16)w0.x, (_Float16)w0.y, (_Float16)w0.z, (_Float16)w0.w,
                (_Float16)w1.x, (_Float16)w1.y, (_Float16)w1.z, (_Float16)w1.w};
            if (kt < 2)
                *(f16x8*)&wlds[wv][j][kt][(size_t)l * 8] = f;
            else
                wreg[j][(kt == 2) ? 0 : kt - 3] = f;
        }
    }

    const int grow = stripe * 4 + quad;   // this lane's global batch row
    float c2[2] = {0.f, 0.f};             // c[row=quad][uu], c[row=quad][uu+128]

    const int* xp = x + (size_t)grow * S_;
    const f32x4 z4 = (f32x4){0.f, 0.f, 0.f, 0.f};

    // acc holds step-s gates at each loop-top; step 0 has no W_hh term.
    f32x4 acc[8];
#pragma unroll
    for (int j = 0; j < 8; ++j) acc[j] = z4;

    // tcv pipeline: tcv = T2h(x_s) at loop top; prefetched during MFMAs.
    f16x4 tcv[2];
    tcv[0] = *(const f16x4*)(T2h + ((size_t)xp[0] * 256 + uu) * 4);
    tcv[1] = *(const f16x4*)(T2h + ((size_t)xp[0] * 256 + uu + 128) * 4);
    int xnext = xp[1];

    // streamed window: kt3 frags preloaded for the first MFMA phase.
    f16x8 wstr[8];
    const _Float16* wpk_lane = Wpk + (size_t)tid * 128;  // 16 frags x 8 elems
#pragma unroll
    for (int j = 0; j < 8; ++j)
        wstr[j] = *(const f16x8*)(wpk_lane + j * 8);

    __syncthreads();   // wlds + zbuf visible (full barrier OK: once)

    for (int s = 0; s < S_; ++s) {
        const bool last = (s == S_ - 1);

        // ---- epilogue LOW (p=0) of step s; save the p=1 gates first.
        float g1[4] = {acc[1][0], acc[3][0], acc[5][0], acc[7][0]};
        {
            float gi = sig_fast (acc[0][0] + (float)tcv[0][0]);
            float gf = sig_fast (acc[2][0] + (float)tcv[0][1]);
            float gg = tanh_fast(acc[4][0] + (float)tcv[0][2]);
            float go = sig_fast (acc[6][0] + (float)tcv[0][3]);
            float cc = gf * c2[0] + gi * gg;
            c2[0] = cc;
            float hv = go * tanh_fast(cc);
            if (!last) hbuf[s & 1][quad][uu] = (_Float16)hv;
            else       hlast[(size_t)grow * H_ + uu] = hv;
        }

        if (last) {   // final epi-high straight to output; no more MFMA.
            float gi = sig_fast (g1[0] + (float)tcv[1][0]);
            float gf = sig_fast (g1[1] + (float)tcv[1][1]);
            float gg = tanh_fast(g1[2] + (float)tcv[1][2]);
            float go = sig_fast (g1[3] + (float)tcv[1][3]);
            float cc = gf * c2[1] + gi * gg;
            float hv = go * tanh_fast(cc);
            hlast[(size_t)grow * H_ + uu + 128] = hv;
            break;
        }

        // h_s LOW visible to all waves (drain-free barrier).
        asm volatile("s_waitcnt lgkmcnt(0)" ::: "memory");
        __builtin_amdgcn_s_barrier();

        // prefetches for step s+1 (resolve under the MFMA phases)
        f16x4 tn0 = *(const f16x4*)(T2h + ((size_t)xnext * 256 + uu) * 4);
        f16x4 tn1 = *(const f16x4*)(T2h + ((size_t)xnext * 256 + uu + 128) * 4);
        if (s + 2 < S_) xnext = xp[s + 2];

        // A row m = l15; real rows {0,4,8,12} hold batch row m/4, the rest
        // read the zero block. k = kt*32 + quad*8 + i.
        const _Float16* ha = ((l15 & 3) == 0)
            ? (&hbuf[s & 1][l15 >> 2][0] + quad * 8)
            : (zbuf + quad * 8);

        // ---- phase B: kt0..3 (h-low only) interleaved with epi-HIGH VALU.
        {   // kt0: z4 C-operand
            f16x8 a = *(const f16x8*)(ha + 0 * 32);
#pragma unroll
            for (int j = 0; j < 8; ++j) {
                f16x8 b = *(const f16x8*)&wlds[wv][j][0][(size_t)l * 8];
                acc[j] = __builtin_amdgcn_mfma_f32_16x16x32_f16(
                    a, b, z4, 0, 0, 0);
            }
        }
        float gi1 = sig_fast(g1[0] + (float)tcv[1][0]);
        float gf1 = sig_fast(g1[1] + (float)tcv[1][1]);
        {   // kt1
            f16x8 a = *(const f16x8*)(ha + 1 * 32);
#pragma unroll
            for (int j = 0; j < 8; ++j) {
                f16x8 b = *(const f16x8*)&wlds[wv][j][1][(size_t)l * 8];
                acc[j] = __builtin_amdgcn_mfma_f32_16x16x32_f16(
                    a, b, acc[j], 0, 0, 0);
            }
        }
        float gg1 = tanh_fast(g1[2] + (float)tcv[1][2]);
        float go1 = sig_fast (g1[3] + (float)tcv[1][3]);
        {   // kt2
            f16x8 a = *(const f16x8*)(ha + 2 * 32);
#pragma unroll
            for (int j = 0; j < 8; ++j)
                acc[j] = __builtin_amdgcn_mfma_f32_16x16x32_f16(
                    a, wreg[j][0], acc[j], 0, 0, 0);
        }
        float cc1 = gf1 * c2[1] + gi1 * gg1;
        c2[1] = cc1;
        float hv1 = go1 * tanh_fast(cc1);
        {   // kt3: streamed window
            f16x8 a = *(const f16x8*)(ha + 3 * 32);
#pragma unroll
            for (int j = 0; j < 8; ++j)
                acc[j] = __builtin_amdgcn_mfma_f32_16x16x32_f16(
                    a, wstr[j], acc[j], 0, 0, 0);
        }
        hbuf[s & 1][quad][uu + 128] = (_Float16)hv1;   // h_s HIGH

        // refill window with kt7 frags; pin below kt3's MFMAs (reg bound).
        __builtin_amdgcn_sched_barrier(0);
#pragma unroll
        for (int j = 0; j < 8; ++j)
            wstr[j] = *(const f16x8*)(wpk_lane + 64 + j * 8);

        // h_s HIGH visible to all waves (drain-free barrier).
        asm volatile("s_waitcnt lgkmcnt(0)" ::: "memory");
        __builtin_amdgcn_s_barrier();

        // ---- phase C: kt4..7 (h-high).
#pragma unroll
        for (int m = 1; m < 4; ++m) {
            f16x8 a = *(const f16x8*)(ha + (m + 3) * 32);
#pragma unroll
            for (int j = 0; j < 8; ++j)
                acc[j] = __builtin_amdgcn_mfma_f32_16x16x32_f16(
                    a, wreg[j][m], acc[j], 0, 0, 0);
        }
        {   // kt7: streamed window (refilled in phase B)
            f16x8 a = *(const f16x8*)(ha + 7 * 32);
#pragma unroll
            for (int j = 0; j < 8; ++j)
                acc[j] = __builtin_amdgcn_mfma_f32_16x16x32_f16(
                    a, wstr[j], acc[j], 0, 0, 0);
        }

        // preload next step's kt3 window (stays in flight; no barrier here
        // - next iter's epi writes the OTHER hbuf parity, so no hazard
        // until the next phase-B barrier).
#pragma unroll
        for (int j = 0; j < 8; ++j)
            wstr[j] = *(const f16x8*)(wpk_lane + j * 8);

        // rotate tcv pipeline
        tcv[0] = tn0;
        tcv[1] = tn1;
    }
}

// ---------------------------------------------------------------- K3: head
__global__ void out_kernel(const float* __restrict__ hlast,
                           const float* __restrict__ W_out,
                           const float* __restrict__ b_out,
                           float* __restrict__ out) {
    const int b = blockIdx.x;    // 256
    const int o = threadIdx.x;   // 128
    __shared__ float hl[H_];
    hl[o]       = hlast[b * H_ + o];
    hl[o + 128] = hlast[b * H_ + o + 128];
    __syncthreads();
    const float4* wp = (const float4*)(W_out + o * H_);
    float acc = 0.f;
#pragma unroll
    for (int i = 0; i < H_ / 4; ++i) {
        float4 w = wp[i];
        acc += w.x * hl[4*i] + w.y * hl[4*i+1] + w.z * hl[4*i+2] + w.w * hl[4*i+3];
    }
    out[b * O_ + o] = acc + b_out[o];
}

// ----------------------------------------------------------------- launcher
extern "C" void kernel_launch(void* const* d_in, const int* in_sizes, int n_in,
                              void* d_out, int out_size, void* d_ws, size_t ws_size,
                              hipStream_t stream) {
    const int*   x     = (const int*)  d_in[0];
    const float* emb   = (const float*)d_in[1];
    const float* W_ih  = (const float*)d_in[2];
    const float* W_hh  = (const float*)d_in[3];
    const float* b_ih  = (const float*)d_in[4];
    const float* b_hh  = (const float*)d_in[5];
    const float* W_out = (const float*)d_in[6];
    const float* b_out = (const float*)d_in[7];
    float* out = (float*)d_out;

    char* ws = (char*)d_ws;
    _Float16* T2h   = (_Float16*)(ws + T_OFF);
    float*    hlast = (float*)(ws + HLAST_OFF);
    _Float16* Wpk   = (_Float16*)(ws + WPK_OFF);

    build_table<<<dim3(V_), dim3(256), 0, stream>>>(emb, W_ih, b_ih, b_hh, T2h);
    prepack<<<dim3(16), dim3(512), 0, stream>>>(W_hh, Wpk);
    lstm_persistent<<<dim3(64), dim3(512), 0, stream>>>(x, W_hh, T2h, Wpk, hlast);
    out_kernel<<<dim3(B_), dim3(O_), 0, stream>>>(hlast, W_out, b_out, out);
}

// Round 16
// 859.344 us; speedup vs baseline: 2.3095x; 2.3095x over previous
//
#include <hip/hip_runtime.h>

// CharNNClassifier: out = (LSTM(emb[x]) last h) @ W_out^T + b_out
// B=256 S=512 V=256 E=128 H=256 4H=1024 O=128, fp32 in/out.
//
// R18 = R15 restored (best verified: 857 us total, lstm 770 us).
//  R17 post-mortem: split-k + 2 barriers/step -> idle 180 -> 5400 cyc/step
//  (barriers RE-phase waves; every sync point costs full serial latency).
//  The single-barrier R15 schedule is the minimum-sync structure.
//  Ceiling accounting (measured over R4..R17):
//   - per-wg MFMA work invariant: 512 tile-ops/step = 2484 cyc (any
//     zero-exchange decomposition; exchange = +4000 cyc, R4).
//   - epilogue VALU serially dependent on MFMA output within the step.
//   - R15 runs 95% issue-busy per active CU (MFMA 57% + VALU 38%);
//     VALU-count diet (R16) and phase overlap (R17) both null/negative.
//  Structure: 64 wgs x 512 thr, 4 batch rows/wg at A rows {0,4,8,12}
//  (row-trick: gates land in reg 0 of every lane -> no bounce). W split:
//  kt0,1 wlds (128 KB) | kt2,4,5,6 wreg[8][4] (128 VGPR) | kt3,7
//  streamed from Wpk[tid][frag] (offset-imm folding); A-frags read once;
//  HSTRIDE 272; drain-free step barrier (lgkmcnt(0) + raw s_barrier).
//  LDS = 128K + 4.25K + 0.5K = 132.75 KB. Regs ~215.

typedef _Float16 f16x8 __attribute__((ext_vector_type(8)));
typedef _Float16 f16x4 __attribute__((ext_vector_type(4)));
typedef float    f32x4 __attribute__((ext_vector_type(4)));

#define B_  256
#define S_  512
#define V_  256
#define E_  128
#define H_  256
#define O_  128

// ws layout (bytes)
#define T_OFF     0u              // T2h: 256*256*4 fp16 = 512 KiB
#define HLAST_OFF (512u << 10)    // hlast: 256*256*4B   = 256 KiB
#define WPK_OFF   (768u << 10)    // Wpk: 16*512*16B     = 128 KiB

// ---------------------------------------------------------------- K1: table
// T2h[v][unit] = fp16x4 {i,f,g,o} pre-activations from the embedding path.
__global__ void build_table(const float* __restrict__ emb,
                            const float* __restrict__ W_ih,
                            const float* __restrict__ b_ih,
                            const float* __restrict__ b_hh,
                            _Float16* __restrict__ T2h) {
    const int v   = blockIdx.x;   // vocab id
    const int tid = threadIdx.x;  // 256 threads = hidden unit

    __shared__ float e[E_];
    if (tid < E_) e[tid] = emb[v * E_ + tid];
    __syncthreads();

    f16x4 tv;
#pragma unroll
    for (int t = 0; t < 4; ++t) {
        const int g = t * 256 + tid;
        const float4* wp = (const float4*)(W_ih + g * E_);
        float acc = 0.f;
#pragma unroll
        for (int i = 0; i < E_ / 4; ++i) {
            float4 w = wp[i];
            acc += w.x * e[4*i] + w.y * e[4*i+1] + w.z * e[4*i+2] + w.w * e[4*i+3];
        }
        tv[t] = (_Float16)(acc + b_ih[g] + b_hh[g]);
    }
    *(f16x4*)(T2h + ((size_t)v * 256 + tid) * 4) = tv;
}

// ------------------------------------------------------- K1b: W-frag prepack
// Wpk[blk=ktS*8+j][tid] = the f16x8 B-fragment thread tid needs for
// (kt = 3 + ktS*4, j). Lane math mirrors the main kernel's prologue.
__global__ void prepack(const float* __restrict__ W_hh,
                        _Float16* __restrict__ Wpk) {
    const int blk = blockIdx.x;      // 0..15 = ktS*8 + j
    const int ktS = blk >> 3;        // 0 -> kt3, 1 -> kt7
    const int j   = blk & 7;
    const int kt  = 3 + ktS * 4;
    const int tid = threadIdx.x;     // 512
    const int wv = tid >> 6, l = tid & 63, l15 = l & 15, quad = l >> 4;
    const int n  = j * 128 + wv * 16 + l15;   // gate column
    const int k0 = kt * 32 + quad * 8;
    const float4* wp = (const float4*)(W_hh + (size_t)n * H_ + k0);
    float4 w0 = wp[0];
    float4 w1 = wp[1];
    f16x8 f = (f16x8){
        (_Float16)w0.x, (_Float16)w0.y, (_Float16)w0.z, (_Float16)w0.w,
        (_Float16)w1.x, (_Float16)w1.y, (_Float16)w1.z, (_Float16)w1.w};
    *(f16x8*)(Wpk + ((size_t)blk * 512 + tid) * 8) = f;
}

// ------------------------------------------------------------ K2: recurrence
// Pre-act bounds: |W_hh row . h| <= 256*(1/16) = 16 hard; |table| < ~5.
// Sigmoid needs no clamp; tanh keeps a +-30 clamp as overflow insurance.
__device__ __forceinline__ float sig_fast(float x) {
    float t = __builtin_amdgcn_exp2f(-1.4426950408889634f * x);
    return __builtin_amdgcn_rcpf(1.f + t);
}
__device__ __forceinline__ float tanh_fast(float x) {
    x = fminf(fmaxf(x, -30.f), 30.f);
    float t = __builtin_amdgcn_exp2f(-2.8853900817779268f * x);  // e^{-2x}
    return (1.f - t) * __builtin_amdgcn_rcpf(1.f + t);
}

#define HSTRIDE 272   // fp16/row: 544 B => row bank-phase 0/8/16/24

__launch_bounds__(512, 2)
__global__ void lstm_persistent(const int* __restrict__ x,
                                const float* __restrict__ W_hh,
                                const _Float16* __restrict__ T2h,
                                const _Float16* __restrict__ Wpk,
                                float* __restrict__ hlast) {
    const int tid    = threadIdx.x;
    const int wv     = tid >> 6;     // wave 0..7
    const int l      = tid & 63;
    const int l15    = l & 15;
    const int quad   = l >> 4;       // 0..3  == this lane's batch row (local)
    const int stripe = blockIdx.x;   // batch rows [stripe*4, +4)
    const int uu     = wv * 16 + l15;    // unit (p=0 half)

    // LDS: 128 KB weights (kt 0..1) + 4-row h dbuf + zero block.
    __shared__ __align__(16) _Float16 wlds[8][8][2][512];   // 128 KiB
    __shared__ __align__(16) _Float16 hbuf[2][4][HSTRIDE];  // 4.25 KiB
    __shared__ __align__(16) _Float16 zbuf[256];            // 512 B zeros

    if (tid < 128) ((int*)zbuf)[tid] = 0;

    // ---- prologue: kt {0,1}->wlds, {2,4,5,6}->wreg, {3,7} streamed later.
    // col n = j*128 + uu; k = kt*32 + quad*8 + i; B[k][n] = W_hh[n][k]
    f16x8 wreg[8][4];   // [j][m]: m=0->kt2, 1->kt4, 2->kt5, 3->kt6
#pragma unroll
    for (int j = 0; j < 8; ++j) {
        const float* wr = W_hh + (size_t)(j * 128 + uu) * H_ + quad * 8;
#pragma unroll
        for (int kt = 0; kt < 7; ++kt) {
            if (kt == 3) continue;   // streamed
            const float4* wp = (const float4*)(wr + kt * 32);
            float4 w0 = wp[0];
            float4 w1 = wp[1];
            f16x8 f = (f16x8){
                (_Float16)w0.x, (_Float16)w0.y, (_Float16)w0.z, (_Float16)w0.w,
                (_Float16)w1.x, (_Float16)w1.y, (_Float16)w1.z, (_Float16)w1.w};
            if (kt < 2)
                *(f16x8*)&wlds[wv][j][kt][(size_t)l * 8] = f;
            else
                wreg[j][(kt == 2) ? 0 : kt - 3] = f;
        }
    }

    const int grow = stripe * 4 + quad;   // this lane's global batch row
    float c2[2] = {0.f, 0.f};             // c[row=quad][uu], c[row=quad][uu+128]

    // x prefetch: 1 step ahead (one row per lane = quad).
    int xv = x[(size_t)grow * S_];

    // single streamed window (32 regs): holds kt3 frags across the step
    // boundary, refilled mid-step with kt7 frags.
    f16x8 wstr[8];
    const _Float16* wpk_lane = Wpk + (size_t)tid * 8;

    __syncthreads();   // wlds + zbuf visible (full barrier OK: once)

    for (int s = 0; s < S_; ++s) {
        // T2h gather for THIS step (consumed in epilogue; MFMAs cover latency)
        f16x4 tcv[2];
        tcv[0] = *(const f16x4*)(T2h + ((size_t)xv * 256 + uu) * 4);
        tcv[1] = *(const f16x4*)(T2h + ((size_t)xv * 256 + uu + 128) * 4);
        if (s + 1 < S_) xv = x[(size_t)grow * S_ + s + 1];

        f32x4 acc[8];
#pragma unroll
        for (int j = 0; j < 8; ++j) acc[j] = (f32x4){0.f, 0.f, 0.f, 0.f};

        if (s > 0) {
            // A row m = l15; real rows m in {0,4,8,12} hold batch row m/4,
            // all other rows read the zero block. k = kt*32 + quad*8 + i.
            const _Float16* ha = ((l15 & 3) == 0)
                ? (&hbuf[(s - 1) & 1][l15 >> 2][0] + quad * 8)
                : (zbuf + quad * 8);

            // ---- pass 0: kt 0..3, each A-frag read ONCE, all 8 j inner.
#pragma unroll
            for (int kt = 0; kt < 2; ++kt) {
                f16x8 a = *(const f16x8*)(ha + kt * 32);
#pragma unroll
                for (int j = 0; j < 8; ++j) {
                    f16x8 b = *(const f16x8*)&wlds[wv][j][kt][(size_t)l * 8];
                    acc[j] = __builtin_amdgcn_mfma_f32_16x16x32_f16(
                        a, b, acc[j], 0, 0, 0);
                }
            }
            {
                f16x8 a = *(const f16x8*)(ha + 2 * 32);
#pragma unroll
                for (int j = 0; j < 8; ++j)
                    acc[j] = __builtin_amdgcn_mfma_f32_16x16x32_f16(
                        a, wreg[j][0], acc[j], 0, 0, 0);
            }
            {
                f16x8 a = *(const f16x8*)(ha + 3 * 32);
#pragma unroll
                for (int j = 0; j < 8; ++j)
                    acc[j] = __builtin_amdgcn_mfma_f32_16x16x32_f16(
                        a, wstr[j], acc[j], 0, 0, 0);
            }

            // refill the window with kt7 frags; pin below kt3's MFMAs so
            // the old and new wstr live ranges don't overlap (reg bound).
            __builtin_amdgcn_sched_barrier(0);
#pragma unroll
            for (int j = 0; j < 8; ++j)
                wstr[j] = *(const f16x8*)(wpk_lane + ((size_t)(8 + j) * 512) * 8);

            // ---- pass 1: kt 4..6 resident, kt 7 streamed (cover = kt4..6).
#pragma unroll
            for (int m = 1; m < 4; ++m) {
                f16x8 a = *(const f16x8*)(ha + (m + 3) * 32);
#pragma unroll
                for (int j = 0; j < 8; ++j)
                    acc[j] = __builtin_amdgcn_mfma_f32_16x16x32_f16(
                        a, wreg[j][m], acc[j], 0, 0, 0);
            }
            {
                f16x8 a = *(const f16x8*)(ha + 7 * 32);
#pragma unroll
                for (int j = 0; j < 8; ++j)
                    acc[j] = __builtin_amdgcn_mfma_f32_16x16x32_f16(
                        a, wstr[j], acc[j], 0, 0, 0);
            }
        }

        // ---- epilogue straight from registers: gate t of unit half p is
        // acc[2t+p][0] (C row 4*quad = reg 0 of this lane).
        const bool last = (s == S_ - 1);
#pragma unroll
        for (int p = 0; p < 2; ++p) {
            float gi = sig_fast (acc[0 + p][0] + (float)tcv[p][0]);
            float gf = sig_fast (acc[2 + p][0] + (float)tcv[p][1]);
            float gg = tanh_fast(acc[4 + p][0] + (float)tcv[p][2]);
            float go = sig_fast (acc[6 + p][0] + (float)tcv[p][3]);
            float cc = gf * c2[p] + gi * gg;
            c2[p] = cc;
            float hv = go * tanh_fast(cc);
            if (!last) {
                hbuf[s & 1][quad][uu + p * 128] = (_Float16)hv;
            } else {
                hlast[(size_t)grow * H_ + uu + p * 128] = hv;
            }
        }

        // preload NEXT step's kt3 frags BEFORE the barrier. With the raw
        // barrier below (NO vmcnt drain), these genuinely stay in flight
        // across the barrier; the counted vmcnt lands at next step's kt3.
        if (!last) {
#pragma unroll
            for (int j = 0; j < 8; ++j)
                wstr[j] = *(const f16x8*)(wpk_lane + ((size_t)j * 512) * 8);
        }

        // drain-free step barrier: lgkmcnt(0) makes this wave's h ds_writes
        // (and its hbuf ds_reads - WAR) complete; s_barrier syncs waves.
        // VMEM loads are register-private: no vmcnt drain needed.
        asm volatile("s_waitcnt lgkmcnt(0)" ::: "memory");
        __builtin_amdgcn_s_barrier();
    }
}

// ---------------------------------------------------------------- K3: head
__global__ void out_kernel(const float* __restrict__ hlast,
                           const float* __restrict__ W_out,
                           const float* __restrict__ b_out,
                           float* __restrict__ out) {
    const int b = blockIdx.x;    // 256
    const int o = threadIdx.x;   // 128
    __shared__ float hl[H_];
    hl[o]       = hlast[b * H_ + o];
    hl[o + 128] = hlast[b * H_ + o + 128];
    __syncthreads();
    const float4* wp = (const float4*)(W_out + o * H_);
    float acc = 0.f;
#pragma unroll
    for (int i = 0; i < H_ / 4; ++i) {
        float4 w = wp[i];
        acc += w.x * hl[4*i] + w.y * hl[4*i+1] + w.z * hl[4*i+2] + w.w * hl[4*i+3];
    }
    out[b * O_ + o] = acc + b_out[o];
}

// ----------------------------------------------------------------- launcher
extern "C" void kernel_launch(void* const* d_in, const int* in_sizes, int n_in,
                              void* d_out, int out_size, void* d_ws, size_t ws_size,
                              hipStream_t stream) {
    const int*   x     = (const int*)  d_in[0];
    const float* emb   = (const float*)d_in[1];
    const float* W_ih  = (const float*)d_in[2];
    const float* W_hh  = (const float*)d_in[3];
    const float* b_ih  = (const float*)d_in[4];
    const float* b_hh  = (const float*)d_in[5];
    const float* W_out = (const float*)d_in[6];
    const float* b_out = (const float*)d_in[7];
    float* out = (float*)d_out;

    char* ws = (char*)d_ws;
    _Float16* T2h   = (_Float16*)(ws + T_OFF);
    float*    hlast = (float*)(ws + HLAST_OFF);
    _Float16* Wpk   = (_Float16*)(ws + WPK_OFF);

    build_table<<<dim3(V_), dim3(256), 0, stream>>>(emb, W_ih, b_ih, b_hh, T2h);
    prepack<<<dim3(16), dim3(512), 0, stream>>>(W_hh, Wpk);
    lstm_persistent<<<dim3(64), dim3(512), 0, stream>>>(x, W_hh, T2h, Wpk, hlast);
    out_kernel<<<dim3(B_), dim3(O_), 0, stream>>>(hlast, W_out, b_out, out);
}